// Round 4
// baseline (251.435 us; speedup 1.0000x reference)
//
#include <hip/hip_runtime.h>
#include <cstdint>
#include <cstddef>

// x[B=32, T=4096, N=256] fp32 -> z same shape.
// Refractory scan: spike at step t iff x>0 and t >= na; then na = t+6.
// Entry state q==k <=> first k steps of chunk blocked. q in [0,5].
//
// R4: R3 showed occupancy was NOT the limiter (67% occ, still 2.2 TB/s,
// slower than R1). The cost is intra-kernel global sync (spin-poll +
// chip-wide phase alignment). Split into two fill-shaped streaming
// kernels with stream order as the only sync: no atomics, no spins,
// no workspace poison.
//   K1 scan: read x, write sign bitmasks (4 MiB) + group maps (1 MiB).
//   K2 emit: read bitmasks + maps (L2-hot), resolve prefixes, write z.
#define BB 32
#define TT 4096
#define NNV 64        // float4 groups per row (N=256)
#define CC 32         // steps per chunk (one u32 bitmask per chain)
#define PSUB 4        // chunks per block (one per 64-lane wave)
#define PG 32         // chunk-groups per chain: T / (CC*PSUB)
#define NCH 256       // chains (N)

// Compose 6-nibble maps: h = "f then g", h[e] = g[f[e]].
__device__ __forceinline__ uint32_t comp6(uint32_t f, uint32_t g) {
    uint32_t h = 0;
    #pragma unroll
    for (int e = 0; e < 6; ++e) {
        const uint32_t fe = (f >> (4 * e)) & 0xFu;
        h |= ((g >> (4 * fe)) & 0xFu) << (4 * e);
    }
    return h;
}

// Per-chunk entry->exit table from a 32-step sign bitmask.
// <=6 spikes per 32 steps (each advances na by 6): 6 branchless ctz iters.
__device__ __forceinline__ uint32_t tbl_from_mask(uint32_t m) {
    uint32_t tbl = 0;
    #pragma unroll
    for (int e = 0; e < 6; ++e) {
        int na = e;
        #pragma unroll
        for (int it = 0; it < 6; ++it) {
            const uint32_t r = (na < 32) ? (m >> na) : 0u;
            const int t = na + (r ? __builtin_ctz(r) : 0);
            na = r ? (t + 6) : na;
        }
        const int q = na > CC ? na - CC : 0;   // exit state in [0,5]
        tbl |= (uint32_t)q << (4 * e);
    }
    return tbl;
}

// K1: pure read-stream. Block = (b, pg) covers 128 steps x 256 chains.
__global__ __launch_bounds__(256) void k_scan(const float* __restrict__ x,
                                              uint4* __restrict__ msk,
                                              uint32_t* __restrict__ gtab) {
    const int tid = threadIdx.x;
    const int pg = blockIdx.x >> 5;
    const int b  = blockIdx.x & 31;
    const int psub = tid >> 6;
    const int n4 = tid & 63;
    const int p = pg * PSUB + psub;

    const float4* __restrict__ xv = reinterpret_cast<const float4*>(x)
        + ((size_t)b * TT + (size_t)p * CC) * NNV + n4;

    uint32_t cur[4] = {0u, 0u, 0u, 0u};
    #pragma unroll
    for (int jb = 0; jb < CC; jb += 8) {
        float4 buf[8];
        #pragma unroll
        for (int u = 0; u < 8; ++u)
            buf[u] = xv[(size_t)(jb + u) * NNV];
        #pragma unroll
        for (int u = 0; u < 8; ++u) {
            const int j = jb + u;
            cur[0] |= (buf[u].x > 0.0f) ? (1u << j) : 0u;
            cur[1] |= (buf[u].y > 0.0f) ? (1u << j) : 0u;
            cur[2] |= (buf[u].z > 0.0f) ? (1u << j) : 0u;
            cur[3] |= (buf[u].w > 0.0f) ? (1u << j) : 0u;
        }
    }

    // Bitmasks out: one 16B store per thread, 1 KB contiguous per wave.
    msk[(size_t)blockIdx.x * 256 + tid] = make_uint4(cur[0], cur[1], cur[2], cur[3]);

    // Group map = t[0] o t[1] o t[2] o t[3], log-depth pairwise in LDS.
    __shared__ uint32_t tbl[PSUB][NCH];
    __shared__ uint32_t aux[2][NCH];
    #pragma unroll
    for (int c = 0; c < 4; ++c)
        tbl[psub][n4 * 4 + c] = tbl_from_mask(cur[c]);
    __syncthreads();
    aux[0][tid] = comp6(tbl[0][tid], tbl[1][tid]);
    aux[1][tid] = comp6(tbl[2][tid], tbl[3][tid]);
    __syncthreads();
    gtab[(size_t)blockIdx.x * 256 + tid] = comp6(aux[0][tid], aux[1][tid]);
}

// K2: pure write-stream. Same block mapping as K1.
__global__ __launch_bounds__(256) void k_emit(const uint4* __restrict__ msk,
                                              const uint32_t* __restrict__ gtab,
                                              float* __restrict__ z) {
    const int tid = threadIdx.x;
    const int pg = blockIdx.x >> 5;
    const int b  = blockIdx.x & 31;
    const int psub = tid >> 6;
    const int n4 = tid & 63;
    const int p = pg * PSUB + psub;

    __shared__ uint32_t gl[PG - 1][NCH];   // predecessor group maps (<=31 KB)
    __shared__ uint32_t tbl[PSUB][NCH];
    __shared__ uint8_t  ent[PSUB][NCH];

    // Predecessor maps (L2-hot: 1 MiB total, each word read by ~31 blocks).
    for (int i = tid; i < pg * NCH; i += 256)
        gl[0][i] = gtab[((size_t)(i >> 8) * 32 + b) * 256 + (i & 255)];

    const uint4 mv = msk[(size_t)blockIdx.x * 256 + tid];
    uint32_t cur[4] = {mv.x, mv.y, mv.z, mv.w};
    #pragma unroll
    for (int c = 0; c < 4; ++c)
        tbl[psub][n4 * 4 + c] = tbl_from_mask(cur[c]);
    __syncthreads();

    // Per-chain prefix walk (tid == chain n): <=31 group hops + 4 chunk hops.
    {
        int e = 0;
        for (int g = 0; g < pg; ++g)
            e = (int)((gl[g][tid] >> (4 * e)) & 0xFu);
        #pragma unroll
        for (int s = 0; s < PSUB; ++s) {
            ent[s][tid] = (uint8_t)e;
            e = (int)((tbl[s][tid] >> (4 * e)) & 0xFu);
        }
    }
    __syncthreads();

    float4* __restrict__ zv = reinterpret_cast<float4*>(z)
        + ((size_t)b * TT + (size_t)p * CC) * NNV + n4;

    const uint32_t e4 = reinterpret_cast<const uint32_t*>(ent[psub])[n4];
    uint32_t spk[4];
    #pragma unroll
    for (int c = 0; c < 4; ++c) {
        const uint32_t m = cur[c];
        int na = (int)((e4 >> (8 * c)) & 0xFFu);
        uint32_t s = 0;
        #pragma unroll
        for (int it = 0; it < 6; ++it) {
            const uint32_t r = (na < 32) ? (m >> na) : 0u;
            const int t = na + (r ? __builtin_ctz(r) : 0);
            s |= r ? (1u << (t & 31)) : 0u;   // t < 32 whenever r != 0
            na = r ? (t + 6) : na;
        }
        spk[c] = s;
    }

    #pragma unroll
    for (int j = 0; j < CC; ++j) {
        float4 o;
        o.x = ((spk[0] >> j) & 1u) ? 1.0f : 0.0f;
        o.y = ((spk[1] >> j) & 1u) ? 1.0f : 0.0f;
        o.z = ((spk[2] >> j) & 1u) ? 1.0f : 0.0f;
        o.w = ((spk[3] >> j) & 1u) ? 1.0f : 0.0f;
        zv[(size_t)j * NNV] = o;
    }
}

extern "C" void kernel_launch(void* const* d_in, const int* in_sizes, int n_in,
                              void* d_out, int out_size, void* d_ws, size_t ws_size,
                              hipStream_t stream) {
    const float* x = (const float*)d_in[0];
    float* z = (float*)d_out;
    uint4* msk = (uint4*)d_ws;                                   // 4 MiB
    uint32_t* gtab = (uint32_t*)((char*)d_ws + (size_t)BB * PG * PSUB * NCH * 4);  // 1 MiB

    // Stream order is the only synchronization: no atomics, no poison.
    k_scan<<<dim3(BB * PG), 256, 0, stream>>>(x, msk, gtab);
    k_emit<<<dim3(BB * PG), 256, 0, stream>>>(msk, gtab, z);
}